// Round 9
// baseline (74.017 us; speedup 1.0000x reference)
//
#include <hip/hip_runtime.h>

#define D_MODEL 256
#define TX 512
#define TM 512

__device__ __forceinline__ float fexp2(float x) { return __builtin_amdgcn_exp2f(x); }
__device__ __forceinline__ float frcp(float x)  { return __builtin_amdgcn_rcpf(x); }

// acc += w / (1 + a*e2)  via magic seed + 1 Halley step (all full-rate VALU, 6 instrs)
__device__ __forceinline__ float evalterm(float a, float e2, float w, float acc) {
    float z = fmaf(a, e2, 1.f);                     // z >= 1, finite
    unsigned zi = __builtin_bit_cast(unsigned, z);
    float y = __builtin_bit_cast(float, 0x7EF311C3u - zi);  // ~5% seed
    float r = fmaf(-z, y, 1.f);                     // e = 1 - z*y
    float u = fmaf(r, r, r);                        // e + e^2
    y = fmaf(y, u, y);                              // y*(1 + e + e^2)  (cubic)
    return fmaf(w, y, acc);
}

// Two NT-GEMMs in one launch; epilogues write exp2(2log2e * value):
//  z=0: E1 [2048][256] = exp2(c*(x · w1^T + b1))           row-major
//  z=1: E2p packed     = exp2(c*(w2 · mem^T))  at [(d>>2)*8192 + gm*4 + (d&3)]
// Grid (32, 4, 2), block 256.
__global__ __launch_bounds__(256) void gemm_exp2(
    const float* __restrict__ x,   const float* __restrict__ mem,
    const float* __restrict__ w1,  const float* __restrict__ b1,
    const float* __restrict__ w2,
    float* __restrict__ E1, float* __restrict__ E2p)
{
    const float C_SCALE = 2.8853900817779268f; // 2*log2(e)
    const float* A; const float* W;
    int r0, n0;
    if (blockIdx.z == 0) { A = x;  W = w1; r0 = blockIdx.x * 64; n0 = blockIdx.y * 64; }
    else                 { A = w2; W = mem; r0 = blockIdx.y * 64; n0 = blockIdx.x * 64; }

    __shared__ float As[16][68];
    __shared__ float Ws[16][68];
    const int tid = threadIdx.x;
    const int tx = tid & 15, ty = tid >> 4;
    const int rl = tid >> 2, g = tid & 3;
    float acc[4][4] = {};
    const float* Ap = A + (size_t)(r0 + rl) * 256 + g * 4;
    const float* Wp = W + (size_t)(n0 + rl) * 256 + g * 4;
    for (int k0 = 0; k0 < 256; k0 += 16) {
        float4 a4 = *(const float4*)(Ap + k0);
        float4 w4 = *(const float4*)(Wp + k0);
        __syncthreads();
        As[g*4+0][rl] = a4.x; As[g*4+1][rl] = a4.y;
        As[g*4+2][rl] = a4.z; As[g*4+3][rl] = a4.w;
        Ws[g*4+0][rl] = w4.x; Ws[g*4+1][rl] = w4.y;
        Ws[g*4+2][rl] = w4.z; Ws[g*4+3][rl] = w4.w;
        __syncthreads();
        #pragma unroll
        for (int kk = 0; kk < 16; ++kk) {
            float4 av = *(const float4*)&As[kk][ty*4];
            float4 wv = *(const float4*)&Ws[kk][tx*4];
            float a_[4] = {av.x, av.y, av.z, av.w};
            float w_[4] = {wv.x, wv.y, wv.z, wv.w};
            #pragma unroll
            for (int i = 0; i < 4; ++i)
                #pragma unroll
                for (int j = 0; j < 4; ++j)
                    acc[i][j] = fmaf(a_[i], w_[j], acc[i][j]);
        }
    }
    if (blockIdx.z == 0) {
        #pragma unroll
        for (int i = 0; i < 4; ++i) {
            const int r = r0 + ty*4 + i;
            #pragma unroll
            for (int j = 0; j < 4; ++j) {
                const int n = n0 + tx*4 + j;
                E1[(size_t)r*256 + n] = fexp2(C_SCALE * (acc[i][j] + b1[n]));
            }
        }
    } else {
        #pragma unroll
        for (int i = 0; i < 4; ++i) {
            const int r = r0 + ty*4 + i;   // d index
            #pragma unroll
            for (int j = 0; j < 4; ++j) {
                const int n = n0 + tx*4 + j;  // gm index
                E2p[(size_t)(r >> 2)*8192 + (size_t)n*4 + (r & 3)] = fexp2(C_SCALE * acc[i][j]);
            }
        }
    }
}

// Fused: S = Wsum - 2*sum_d w[d]/(1+E1*E2), mask, softmax, single-pass PV.
// Grid 1024 (= B*TX/2), block 256 (4 waves). Block owns 2 x-rows;
// thread t owns m = t and m = t+256.
__global__ __launch_bounds__(256) void fused_tanh_attn(
    const float* __restrict__ E1,     // [B*TX, D]
    const float* __restrict__ E2p,    // packed [(d>>2)][gm][4]
    const float* __restrict__ memory, // [B, TM, D]
    const int*   __restrict__ mask,   // [B, TM]
    const float* __restrict__ wst,    // [D]
    float* __restrict__ out,          // [B*TX, D]
    float* __restrict__ Sout)         // [B*TX, TM]
{
    const float LOG2E = 1.4426950408889634f;
    const int t = threadIdx.x;
    // XCD-aware bijective swizzle (1024 = 8*128): batch b -> 2 XCDs
    const int blk = (int)((blockIdx.x & 7) * 128 + (blockIdx.x >> 3));
    const int b = blk >> 8;                // 256 blocks per batch
    const int x0 = (blk & 255) * 2;
    const int wave = t >> 6, lane = t & 63;

    __shared__ float i1R[2][D_MODEL];       // 2 KB
    __shared__ float wsh[D_MODEL];          // 1 KB
    __shared__ float P[2][TM];              // 4 KB
    __shared__ float mneg[TM];              // 2 KB
    __shared__ float opart[2][4][D_MODEL];  // 8 KB
    __shared__ float wpart[4];

    // stage E1 rows, wst, mask
    {
        const float* i1g = E1 + ((size_t)b * TX + x0) * D_MODEL;
        const int row = t >> 7, col2 = (t & 127) * 2;
        float2 v = *(const float2*)(i1g + (size_t)row * D_MODEL + col2);
        *(float2*)&i1R[row][col2] = v;
    }
    wsh[t] = wst[t];
    mneg[t]       = mask[b*TM + t]       ? 0.f : -__builtin_inff();
    mneg[t + 256] = mask[b*TM + t + 256] ? 0.f : -__builtin_inff();

    // Wsum = sum(wst)
    {
        float s = wst[t];
        #pragma unroll
        for (int off = 32; off > 0; off >>= 1) s += __shfl_xor(s, off);
        if (lane == 0) wpart[wave] = s;
    }

    // first E2 group loads (both m streams)
    const float* e2ptrA = E2p + ((size_t)b * TM + t) * 4;
    const float* e2ptrB = e2ptrA + 1024;   // m + 256
    float4 e2a = *(const float4*)e2ptrA;
    float4 e2b = *(const float4*)e2ptrB;

    __syncthreads();
    const float Wsum = wpart[0] + wpart[1] + wpart[2] + wpart[3];

    // main loop: 64 groups of 4 d; 1-deep prefetch; magic+Halley reciprocal
    float accA0 = 0.f, accA1 = 0.f, accB0 = 0.f, accB1 = 0.f;
    #pragma unroll 2
    for (int gg = 0; gg < 64; ++gg) {
        float4 e2an = e2a, e2bn = e2b;
        if (gg < 63) {
            e2an = *(const float4*)(e2ptrA + (size_t)(gg + 1) * 8192);
            e2bn = *(const float4*)(e2ptrB + (size_t)(gg + 1) * 8192);
        }
        float4 a0 = *(const float4*)&i1R[0][gg * 4];
        float4 a1 = *(const float4*)&i1R[1][gg * 4];
        float4 w4 = *(const float4*)&wsh[gg * 4];
        accA0 = evalterm(a0.x, e2a.x, w4.x, accA0);
        accA0 = evalterm(a0.y, e2a.y, w4.y, accA0);
        accA0 = evalterm(a0.z, e2a.z, w4.z, accA0);
        accA0 = evalterm(a0.w, e2a.w, w4.w, accA0);
        accA1 = evalterm(a1.x, e2a.x, w4.x, accA1);
        accA1 = evalterm(a1.y, e2a.y, w4.y, accA1);
        accA1 = evalterm(a1.z, e2a.z, w4.z, accA1);
        accA1 = evalterm(a1.w, e2a.w, w4.w, accA1);
        accB0 = evalterm(a0.x, e2b.x, w4.x, accB0);
        accB0 = evalterm(a0.y, e2b.y, w4.y, accB0);
        accB0 = evalterm(a0.z, e2b.z, w4.z, accB0);
        accB0 = evalterm(a0.w, e2b.w, w4.w, accB0);
        accB1 = evalterm(a1.x, e2b.x, w4.x, accB1);
        accB1 = evalterm(a1.y, e2b.y, w4.y, accB1);
        accB1 = evalterm(a1.z, e2b.z, w4.z, accB1);
        accB1 = evalterm(a1.w, e2b.w, w4.w, accB1);
        e2a = e2an; e2b = e2bn;
    }

    // scores with mask
    {
        P[0][t]       = Wsum - 2.f * accA0 + mneg[t];
        P[1][t]       = Wsum - 2.f * accA1 + mneg[t];
        P[0][t + 256] = Wsum - 2.f * accB0 + mneg[t + 256];
        P[1][t + 256] = Wsum - 2.f * accB1 + mneg[t + 256];
    }
    __syncthreads();

    // softmax: wave 0 -> row 0, wave 1 -> row 1 (8 values per lane)
    if (wave < 2) {
        const int xx = wave;
        float4 u0 = *(const float4*)&P[xx][lane * 8];
        float4 u1 = *(const float4*)&P[xx][lane * 8 + 4];
        float v[8] = {u0.x,u0.y,u0.z,u0.w,u1.x,u1.y,u1.z,u1.w};
        float mx = v[0];
        #pragma unroll
        for (int q = 1; q < 8; ++q) mx = fmaxf(mx, v[q]);
        #pragma unroll
        for (int off = 32; off > 0; off >>= 1) mx = fmaxf(mx, __shfl_xor(mx, off));
        float e[8];
        float sum = 0.f;
        #pragma unroll
        for (int q = 0; q < 8; ++q) { e[q] = fexp2((v[q] - mx) * LOG2E); sum += e[q]; }
        #pragma unroll
        for (int off = 32; off > 0; off >>= 1) sum += __shfl_xor(sum, off);
        const float inv = frcp(sum);
        float4 p0 = {e[0]*inv, e[1]*inv, e[2]*inv, e[3]*inv};
        float4 p1 = {e[4]*inv, e[5]*inv, e[6]*inv, e[7]*inv};
        *(float4*)&P[xx][lane*8]   = p0;
        *(float4*)&P[xx][lane*8+4] = p1;
        float* Sg = Sout + ((size_t)b*TX + x0 + xx) * TM + lane*8;
        *(float4*)Sg     = p0;
        *(float4*)(Sg+4) = p1;
    }
    __syncthreads();

    // PV single-pass: wave w owns m-quarter [w*128, w*128+128); both rows per load.
    // Each memory element read exactly once per block.
    {
        const int m0 = wave * 128;
        const float* memp = memory + ((size_t)b * TM + m0) * D_MODEL + lane * 4;
        float4 o0 = {0,0,0,0}, o1 = {0,0,0,0};
        #pragma unroll 4
        for (int mm = 0; mm < 128; ++mm) {
            float4 mv = *(const float4*)(memp + (size_t)mm * D_MODEL);
            const float p0 = P[0][m0 + mm];
            const float p1 = P[1][m0 + mm];
            o0.x = fmaf(p0, mv.x, o0.x); o0.y = fmaf(p0, mv.y, o0.y);
            o0.z = fmaf(p0, mv.z, o0.z); o0.w = fmaf(p0, mv.w, o0.w);
            o1.x = fmaf(p1, mv.x, o1.x); o1.y = fmaf(p1, mv.y, o1.y);
            o1.z = fmaf(p1, mv.z, o1.z); o1.w = fmaf(p1, mv.w, o1.w);
        }
        *(float4*)&opart[0][wave][lane*4] = o0;
        *(float4*)&opart[1][wave][lane*4] = o1;
    }
    __syncthreads();

    // combine quarters: 512 outputs, 2 per thread
    {
        #pragma unroll
        for (int k = 0; k < 2; ++k) {
            const int idx = t + k * 256;
            const int row = idx >> 8, d0 = idx & 255;
            float s = opart[row][0][d0] + opart[row][1][d0]
                    + opart[row][2][d0] + opart[row][3][d0];
            out[((size_t)b*TX + x0 + row) * D_MODEL + d0] = s;
        }
    }
}

extern "C" void kernel_launch(void* const* d_in, const int* in_sizes, int n_in,
                              void* d_out, int out_size, void* d_ws, size_t ws_size,
                              hipStream_t stream) {
    const float* x    = (const float*)d_in[0];
    const float* mem  = (const float*)d_in[1];
    const int*   mask = (const int*)d_in[2];
    const float* w1   = (const float*)d_in[3];
    const float* b1   = (const float*)d_in[4];
    const float* w2   = (const float*)d_in[5];
    const float* wst  = (const float*)d_in[6];

    float* out  = (float*)d_out;                  // [4*512*256]
    float* Sout = out + 4 * 512 * 256;            // [4*512*512]
    float* E1   = (float*)d_ws;                   // 524288 floats (2 MB), [2048][256]
    float* E2p  = E1 + 4 * 512 * 256;             // 524288 floats (2 MB), packed

    dim3 gg(32, 4, 2);
    gemm_exp2<<<gg, 256, 0, stream>>>(x, mem, w1, b1, w2, E1, E2p);
    fused_tanh_attn<<<1024, 256, 0, stream>>>(E1, E2p, mem, mask, wst, out, Sout);
}

// Round 10
// 67.519 us; speedup vs baseline: 1.0963x; 1.0963x over previous
//
#include <hip/hip_runtime.h>

#define D_MODEL 256
#define TX 512
#define TM 512

__device__ __forceinline__ float fexp2(float x) { return __builtin_amdgcn_exp2f(x); }
__device__ __forceinline__ float frcp(float x)  { return __builtin_amdgcn_rcpf(x); }

// acc += sum_{i=0..3} w[i]/(1+a[i]*e[i])  with ONE v_rcp_f32.
// N/D form: p_i = 1+a_i e_i; D = (p1 p2)(p3 p4);
// N = p34*(w1 p2 + w2 p1) + p12*(w3 p4 + w4 p3). Exact algebra.
__device__ __forceinline__ float quad(float4 a, float4 e, float4 w, float acc) {
    float p1 = fmaf(a.x, e.x, 1.f);
    float p2 = fmaf(a.y, e.y, 1.f);
    float p3 = fmaf(a.z, e.z, 1.f);
    float p4 = fmaf(a.w, e.w, 1.f);
    float p12 = p1 * p2;
    float p34 = p3 * p4;
    float q12 = fmaf(w.x, p2, w.y * p1);
    float q34 = fmaf(w.z, p4, w.w * p3);
    float N   = fmaf(q12, p34, q34 * p12);
    float D   = p12 * p34;
    return fmaf(N, frcp(D), acc);
}

// Two NT-GEMMs in one launch; epilogues write exp2(2log2e * value):
//  z=0: E1 [2048][256] = exp2(c*(x · w1^T + b1))           row-major
//  z=1: E2p packed     = exp2(c*(w2 · mem^T))  at [(d>>2)*8192 + gm*4 + (d&3)]
// Grid (32, 4, 2), block 256.
__global__ __launch_bounds__(256) void gemm_exp2(
    const float* __restrict__ x,   const float* __restrict__ mem,
    const float* __restrict__ w1,  const float* __restrict__ b1,
    const float* __restrict__ w2,
    float* __restrict__ E1, float* __restrict__ E2p)
{
    const float C_SCALE = 2.8853900817779268f; // 2*log2(e)
    const float* A; const float* W;
    int r0, n0;
    if (blockIdx.z == 0) { A = x;  W = w1; r0 = blockIdx.x * 64; n0 = blockIdx.y * 64; }
    else                 { A = w2; W = mem; r0 = blockIdx.y * 64; n0 = blockIdx.x * 64; }

    __shared__ float As[16][68];
    __shared__ float Ws[16][68];
    const int tid = threadIdx.x;
    const int tx = tid & 15, ty = tid >> 4;
    const int rl = tid >> 2, g = tid & 3;
    float acc[4][4] = {};
    const float* Ap = A + (size_t)(r0 + rl) * 256 + g * 4;
    const float* Wp = W + (size_t)(n0 + rl) * 256 + g * 4;
    for (int k0 = 0; k0 < 256; k0 += 16) {
        float4 a4 = *(const float4*)(Ap + k0);
        float4 w4 = *(const float4*)(Wp + k0);
        __syncthreads();
        As[g*4+0][rl] = a4.x; As[g*4+1][rl] = a4.y;
        As[g*4+2][rl] = a4.z; As[g*4+3][rl] = a4.w;
        Ws[g*4+0][rl] = w4.x; Ws[g*4+1][rl] = w4.y;
        Ws[g*4+2][rl] = w4.z; Ws[g*4+3][rl] = w4.w;
        __syncthreads();
        #pragma unroll
        for (int kk = 0; kk < 16; ++kk) {
            float4 av = *(const float4*)&As[kk][ty*4];
            float4 wv = *(const float4*)&Ws[kk][tx*4];
            float a_[4] = {av.x, av.y, av.z, av.w};
            float w_[4] = {wv.x, wv.y, wv.z, wv.w};
            #pragma unroll
            for (int i = 0; i < 4; ++i)
                #pragma unroll
                for (int j = 0; j < 4; ++j)
                    acc[i][j] = fmaf(a_[i], w_[j], acc[i][j]);
        }
    }
    if (blockIdx.z == 0) {
        #pragma unroll
        for (int i = 0; i < 4; ++i) {
            const int r = r0 + ty*4 + i;
            #pragma unroll
            for (int j = 0; j < 4; ++j) {
                const int n = n0 + tx*4 + j;
                E1[(size_t)r*256 + n] = fexp2(C_SCALE * (acc[i][j] + b1[n]));
            }
        }
    } else {
        #pragma unroll
        for (int i = 0; i < 4; ++i) {
            const int r = r0 + ty*4 + i;   // d index
            #pragma unroll
            for (int j = 0; j < 4; ++j) {
                const int n = n0 + tx*4 + j;  // gm index
                E2p[(size_t)(r >> 2)*8192 + (size_t)n*4 + (r & 3)] = fexp2(C_SCALE * acc[i][j]);
            }
        }
    }
}

// Fused: S = Wsum - 2*sum_d w[d]/(1+E1*E2), mask, softmax, single-pass PV.
// Grid 1024 (= B*TX/2), block 256 (4 waves). Block owns 2 x-rows;
// thread t owns m = t and m = t+256.
__global__ __launch_bounds__(256) void fused_tanh_attn(
    const float* __restrict__ E1,     // [B*TX, D]
    const float* __restrict__ E2p,    // packed [(d>>2)][gm][4]
    const float* __restrict__ memory, // [B, TM, D]
    const int*   __restrict__ mask,   // [B, TM]
    const float* __restrict__ wst,    // [D]
    float* __restrict__ out,          // [B*TX, D]
    float* __restrict__ Sout)         // [B*TX, TM]
{
    const float LOG2E = 1.4426950408889634f;
    const int t = threadIdx.x;
    // XCD-aware bijective swizzle (1024 = 8*128): batch b -> 2 XCDs
    const int blk = (int)((blockIdx.x & 7) * 128 + (blockIdx.x >> 3));
    const int b = blk >> 8;                // 256 blocks per batch
    const int x0 = (blk & 255) * 2;
    const int wave = t >> 6, lane = t & 63;

    __shared__ float i1R[2][D_MODEL];       // 2 KB
    __shared__ float wsh[D_MODEL];          // 1 KB
    __shared__ float P[2][TM];              // 4 KB
    __shared__ float mneg[TM];              // 2 KB
    __shared__ float opart[2][4][D_MODEL];  // 8 KB
    __shared__ float wpart[4];

    // stage E1 rows, wst, mask
    {
        const float* i1g = E1 + ((size_t)b * TX + x0) * D_MODEL;
        const int row = t >> 7, col2 = (t & 127) * 2;
        float2 v = *(const float2*)(i1g + (size_t)row * D_MODEL + col2);
        *(float2*)&i1R[row][col2] = v;
    }
    wsh[t] = wst[t];
    mneg[t]       = mask[b*TM + t]       ? 0.f : -__builtin_inff();
    mneg[t + 256] = mask[b*TM + t + 256] ? 0.f : -__builtin_inff();

    // Wsum = sum(wst)
    {
        float s = wst[t];
        #pragma unroll
        for (int off = 32; off > 0; off >>= 1) s += __shfl_xor(s, off);
        if (lane == 0) wpart[wave] = s;
    }

    // first E2 group loads (both m streams)
    const float* e2ptrA = E2p + ((size_t)b * TM + t) * 4;
    const float* e2ptrB = e2ptrA + 1024;   // m + 256
    float4 e2a = *(const float4*)e2ptrA;
    float4 e2b = *(const float4*)e2ptrB;

    __syncthreads();
    const float Wsum = wpart[0] + wpart[1] + wpart[2] + wpart[3];

    // main loop: 64 groups of 4 d; 1-deep prefetch; one rcp per quad
    float accA0 = 0.f, accA1 = 0.f, accB0 = 0.f, accB1 = 0.f;
    #pragma unroll 2
    for (int gg = 0; gg < 64; ++gg) {
        float4 e2an = e2a, e2bn = e2b;
        if (gg < 63) {
            e2an = *(const float4*)(e2ptrA + (size_t)(gg + 1) * 8192);
            e2bn = *(const float4*)(e2ptrB + (size_t)(gg + 1) * 8192);
        }
        float4 a0 = *(const float4*)&i1R[0][gg * 4];
        float4 a1 = *(const float4*)&i1R[1][gg * 4];
        float4 w4 = *(const float4*)&wsh[gg * 4];
        accA0 = quad(a0, e2a, w4, accA0);
        accA1 = quad(a1, e2a, w4, accA1);
        accB0 = quad(a0, e2b, w4, accB0);
        accB1 = quad(a1, e2b, w4, accB1);
        e2a = e2an; e2b = e2bn;
    }

    // scores with mask
    {
        P[0][t]       = Wsum - 2.f * accA0 + mneg[t];
        P[1][t]       = Wsum - 2.f * accA1 + mneg[t];
        P[0][t + 256] = Wsum - 2.f * accB0 + mneg[t + 256];
        P[1][t + 256] = Wsum - 2.f * accB1 + mneg[t + 256];
    }
    __syncthreads();

    // softmax: wave 0 -> row 0, wave 1 -> row 1 (8 values per lane)
    if (wave < 2) {
        const int xx = wave;
        float4 u0 = *(const float4*)&P[xx][lane * 8];
        float4 u1 = *(const float4*)&P[xx][lane * 8 + 4];
        float v[8] = {u0.x,u0.y,u0.z,u0.w,u1.x,u1.y,u1.z,u1.w};
        float mx = v[0];
        #pragma unroll
        for (int q = 1; q < 8; ++q) mx = fmaxf(mx, v[q]);
        #pragma unroll
        for (int off = 32; off > 0; off >>= 1) mx = fmaxf(mx, __shfl_xor(mx, off));
        float e[8];
        float sum = 0.f;
        #pragma unroll
        for (int q = 0; q < 8; ++q) { e[q] = fexp2((v[q] - mx) * LOG2E); sum += e[q]; }
        #pragma unroll
        for (int off = 32; off > 0; off >>= 1) sum += __shfl_xor(sum, off);
        const float inv = frcp(sum);
        float4 p0 = {e[0]*inv, e[1]*inv, e[2]*inv, e[3]*inv};
        float4 p1 = {e[4]*inv, e[5]*inv, e[6]*inv, e[7]*inv};
        *(float4*)&P[xx][lane*8]   = p0;
        *(float4*)&P[xx][lane*8+4] = p1;
        float* Sg = Sout + ((size_t)b*TX + x0 + xx) * TM + lane*8;
        *(float4*)Sg     = p0;
        *(float4*)(Sg+4) = p1;
    }
    __syncthreads();

    // PV single-pass: wave w owns m-quarter [w*128, w*128+128); both rows per load.
    // Each memory element read exactly once per block.
    {
        const int m0 = wave * 128;
        const float* memp = memory + ((size_t)b * TM + m0) * D_MODEL + lane * 4;
        float4 o0 = {0,0,0,0}, o1 = {0,0,0,0};
        #pragma unroll 4
        for (int mm = 0; mm < 128; ++mm) {
            float4 mv = *(const float4*)(memp + (size_t)mm * D_MODEL);
            const float p0 = P[0][m0 + mm];
            const float p1 = P[1][m0 + mm];
            o0.x = fmaf(p0, mv.x, o0.x); o0.y = fmaf(p0, mv.y, o0.y);
            o0.z = fmaf(p0, mv.z, o0.z); o0.w = fmaf(p0, mv.w, o0.w);
            o1.x = fmaf(p1, mv.x, o1.x); o1.y = fmaf(p1, mv.y, o1.y);
            o1.z = fmaf(p1, mv.z, o1.z); o1.w = fmaf(p1, mv.w, o1.w);
        }
        *(float4*)&opart[0][wave][lane*4] = o0;
        *(float4*)&opart[1][wave][lane*4] = o1;
    }
    __syncthreads();

    // combine quarters: 512 outputs, 2 per thread
    {
        #pragma unroll
        for (int k = 0; k < 2; ++k) {
            const int idx = t + k * 256;
            const int row = idx >> 8, d0 = idx & 255;
            float s = opart[row][0][d0] + opart[row][1][d0]
                    + opart[row][2][d0] + opart[row][3][d0];
            out[((size_t)b*TX + x0 + row) * D_MODEL + d0] = s;
        }
    }
}

extern "C" void kernel_launch(void* const* d_in, const int* in_sizes, int n_in,
                              void* d_out, int out_size, void* d_ws, size_t ws_size,
                              hipStream_t stream) {
    const float* x    = (const float*)d_in[0];
    const float* mem  = (const float*)d_in[1];
    const int*   mask = (const int*)d_in[2];
    const float* w1   = (const float*)d_in[3];
    const float* b1   = (const float*)d_in[4];
    const float* w2   = (const float*)d_in[5];
    const float* wst  = (const float*)d_in[6];

    float* out  = (float*)d_out;                  // [4*512*256]
    float* Sout = out + 4 * 512 * 256;            // [4*512*512]
    float* E1   = (float*)d_ws;                   // 524288 floats (2 MB), [2048][256]
    float* E2p  = E1 + 4 * 512 * 256;             // 524288 floats (2 MB), packed

    dim3 gg(32, 4, 2);
    gemm_exp2<<<gg, 256, 0, stream>>>(x, mem, w1, b1, w2, E1, E2p);
    fused_tanh_attn<<<1024, 256, 0, stream>>>(E1, E2p, mem, mask, wst, out, Sout);
}

// Round 11
// 56.430 us; speedup vs baseline: 1.3117x; 1.1965x over previous
//
#include <hip/hip_runtime.h>

#define D_MODEL 256
#define TX 512
#define TM 512

__device__ __forceinline__ float fexp2(float x) { return __builtin_amdgcn_exp2f(x); }
__device__ __forceinline__ float frcp(float x)  { return __builtin_amdgcn_rcpf(x); }

// acc += sum_{i=0..3} w[i]/(1+a[i]*e[i])  with ONE v_rcp_f32 (exact algebra).
__device__ __forceinline__ float quad(float4 a, float4 e, float4 w, float acc) {
    float p1 = fmaf(a.x, e.x, 1.f);
    float p2 = fmaf(a.y, e.y, 1.f);
    float p3 = fmaf(a.z, e.z, 1.f);
    float p4 = fmaf(a.w, e.w, 1.f);
    float p12 = p1 * p2;
    float p34 = p3 * p4;
    float q12 = fmaf(w.x, p2, w.y * p1);
    float q34 = fmaf(w.z, p4, w.w * p3);
    float N   = fmaf(q12, p34, q34 * p12);
    float D   = p12 * p34;
    return fmaf(N, frcp(D), acc);
}

// Two NT-GEMMs in one launch; double-buffered LDS (1 barrier/K-step).
//  z=0: E1 [2048][256] = exp2(c*(x · w1^T + b1))
//  z=1: E2p packed     = exp2(c*(w2 · mem^T)) at [(d>>2)*8192 + gm*4 + (d&3)]
// Grid (32, 4, 2), block 256.
__global__ __launch_bounds__(256) void gemm_exp2(
    const float* __restrict__ x,   const float* __restrict__ mem,
    const float* __restrict__ w1,  const float* __restrict__ b1,
    const float* __restrict__ w2,
    float* __restrict__ E1, float* __restrict__ E2p)
{
    const float C_SCALE = 2.8853900817779268f; // 2*log2(e)
    const float* A; const float* W;
    int r0, n0;
    if (blockIdx.z == 0) { A = x;  W = w1; r0 = blockIdx.x * 64; n0 = blockIdx.y * 64; }
    else                 { A = w2; W = mem; r0 = blockIdx.y * 64; n0 = blockIdx.x * 64; }

    __shared__ float As[2][16][68];
    __shared__ float Ws[2][16][68];
    const int tid = threadIdx.x;
    const int tx = tid & 15, ty = tid >> 4;
    const int rl = tid >> 2, g = tid & 3;
    float acc[4][4] = {};
    const float* Ap = A + (size_t)(r0 + rl) * 256 + g * 4;
    const float* Wp = W + (size_t)(n0 + rl) * 256 + g * 4;

    {   // prologue: stage k0 = 0 into buffer 0
        float4 a4 = *(const float4*)Ap;
        float4 w4 = *(const float4*)Wp;
        As[0][g*4+0][rl] = a4.x; As[0][g*4+1][rl] = a4.y;
        As[0][g*4+2][rl] = a4.z; As[0][g*4+3][rl] = a4.w;
        Ws[0][g*4+0][rl] = w4.x; Ws[0][g*4+1][rl] = w4.y;
        Ws[0][g*4+2][rl] = w4.z; Ws[0][g*4+3][rl] = w4.w;
    }
    __syncthreads();

    for (int k0 = 0; k0 < 16; ++k0) {
        const int cur = k0 & 1;
        float4 an, wn;
        if (k0 < 15) {
            an = *(const float4*)(Ap + (k0 + 1) * 16);
            wn = *(const float4*)(Wp + (k0 + 1) * 16);
        }
        #pragma unroll
        for (int kk = 0; kk < 16; ++kk) {
            float4 av = *(const float4*)&As[cur][kk][ty*4];
            float4 wv = *(const float4*)&Ws[cur][kk][tx*4];
            float a_[4] = {av.x, av.y, av.z, av.w};
            float w_[4] = {wv.x, wv.y, wv.z, wv.w};
            #pragma unroll
            for (int i = 0; i < 4; ++i)
                #pragma unroll
                for (int j = 0; j < 4; ++j)
                    acc[i][j] = fmaf(a_[i], w_[j], acc[i][j]);
        }
        if (k0 < 15) {
            const int nxt = cur ^ 1;
            As[nxt][g*4+0][rl] = an.x; As[nxt][g*4+1][rl] = an.y;
            As[nxt][g*4+2][rl] = an.z; As[nxt][g*4+3][rl] = an.w;
            Ws[nxt][g*4+0][rl] = wn.x; Ws[nxt][g*4+1][rl] = wn.y;
            Ws[nxt][g*4+2][rl] = wn.z; Ws[nxt][g*4+3][rl] = wn.w;
            __syncthreads();
        }
    }

    if (blockIdx.z == 0) {
        #pragma unroll
        for (int i = 0; i < 4; ++i) {
            const int r = r0 + ty*4 + i;
            #pragma unroll
            for (int j = 0; j < 4; ++j) {
                const int n = n0 + tx*4 + j;
                E1[(size_t)r*256 + n] = fexp2(C_SCALE * (acc[i][j] + b1[n]));
            }
        }
    } else {
        #pragma unroll
        for (int i = 0; i < 4; ++i) {
            const int r = r0 + ty*4 + i;   // d index
            #pragma unroll
            for (int j = 0; j < 4; ++j) {
                const int n = n0 + tx*4 + j;  // gm index
                E2p[(size_t)(r >> 2)*8192 + (size_t)n*4 + (r & 3)] = fexp2(C_SCALE * acc[i][j]);
            }
        }
    }
}

// Fused: S = Wsum - 2*sum_d w[d]/(1+E1*E2), mask, softmax, single-pass PV.
// Grid 512 (= B*TX/4), block 512 (8 waves). Block owns 4 x-rows.
// Thread t: tm = t&255 -> m in {tm, tm+256}; dh = t>>8 -> d-half (128 d).
__global__ __launch_bounds__(512) void fused_tanh_attn(
    const float* __restrict__ E1,     // [B*TX, D]
    const float* __restrict__ E2p,    // packed [(d>>2)][gm][4]
    const float* __restrict__ memory, // [B, TM, D]
    const int*   __restrict__ mask,   // [B, TM]
    const float* __restrict__ wst,    // [D]
    float* __restrict__ out,          // [B*TX, D]
    float* __restrict__ Sout)         // [B*TX, TM]
{
    const float LOG2E = 1.4426950408889634f;
    const int t = threadIdx.x;
    // XCD-aware bijective swizzle (512 = 8*64): each XCD gets 64 contiguous blocks
    const int blk = (int)((blockIdx.x & 7) * 64 + (blockIdx.x >> 3));
    const int b = blk >> 7;                // 128 blocks per batch
    const int x0 = (blk & 127) * 4;
    const int wave = t >> 6, lane = t & 63;
    const int tm = t & 255;
    const int dh = t >> 8;                 // 0 or 1

    __shared__ float i1R[4][D_MODEL];       // 4 KB
    __shared__ float wsh[D_MODEL];          // 1 KB
    __shared__ float P[4][TM];              // 8 KB
    __shared__ float mneg[TM];              // 2 KB
    __shared__ float opart[8][4][D_MODEL];  // 32 KB
    __shared__ float wpart[8];

    // stage E1 rows, wst, mask
    {
        const float* i1g = E1 + ((size_t)b * TX + x0) * D_MODEL;
        const int row = t >> 7, col2 = (t & 127) * 2;
        float2 v = *(const float2*)(i1g + (size_t)row * D_MODEL + col2);
        *(float2*)&i1R[row][col2] = v;
    }
    if (t < 256) wsh[t] = wst[t];
    mneg[t] = mask[b*TM + t] ? 0.f : -__builtin_inff();

    // Wsum = sum(wst)
    {
        float s = (t < 256) ? wst[t] : 0.f;
        #pragma unroll
        for (int off = 32; off > 0; off >>= 1) s += __shfl_xor(s, off);
        if (lane == 0) wpart[wave] = s;
    }

    // first E2 group loads (both m streams, this thread's d-half)
    const int g0 = dh * 32;
    const float* e2ptrA = E2p + ((size_t)b * TM + tm) * 4;
    const float* e2ptrB = e2ptrA + 1024;   // m + 256
    float4 e2a = *(const float4*)(e2ptrA + (size_t)g0 * 8192);
    float4 e2b = *(const float4*)(e2ptrB + (size_t)g0 * 8192);

    __syncthreads();
    const float Wsum = wpart[0] + wpart[1] + wpart[2] + wpart[3]
                     + wpart[4] + wpart[5] + wpart[6] + wpart[7];

    // main loop: 32 groups of 4 d; 1-deep prefetch; one rcp per quad
    float accA[4] = {}, accB[4] = {};
    #pragma unroll 2
    for (int gi = 0; gi < 32; ++gi) {
        const int g = g0 + gi;
        float4 e2an = e2a, e2bn = e2b;
        if (gi < 31) {
            e2an = *(const float4*)(e2ptrA + (size_t)(g + 1) * 8192);
            e2bn = *(const float4*)(e2ptrB + (size_t)(g + 1) * 8192);
        }
        float4 w4 = *(const float4*)&wsh[g * 4];
        #pragma unroll
        for (int r = 0; r < 4; ++r) {
            float4 a = *(const float4*)&i1R[r][g * 4];
            accA[r] = quad(a, e2a, w4, accA[r]);
            accB[r] = quad(a, e2b, w4, accB[r]);
        }
        e2a = e2an; e2b = e2bn;
    }

    // combine d-halves through P, apply Wsum/mask
    if (dh == 0) {
        #pragma unroll
        for (int r = 0; r < 4; ++r) {
            P[r][tm]       = accA[r];
            P[r][tm + 256] = accB[r];
        }
    }
    __syncthreads();
    if (dh == 1) {
        const float mnA = mneg[tm], mnB = mneg[tm + 256];
        #pragma unroll
        for (int r = 0; r < 4; ++r) {
            P[r][tm]       = Wsum - 2.f * (P[r][tm]       + accA[r]) + mnA;
            P[r][tm + 256] = Wsum - 2.f * (P[r][tm + 256] + accB[r]) + mnB;
        }
    }
    __syncthreads();

    // softmax: waves 0..3 -> rows 0..3 (8 values per lane)
    if (wave < 4) {
        const int xx = wave;
        float4 u0 = *(const float4*)&P[xx][lane * 8];
        float4 u1 = *(const float4*)&P[xx][lane * 8 + 4];
        float v[8] = {u0.x,u0.y,u0.z,u0.w,u1.x,u1.y,u1.z,u1.w};
        float mx = v[0];
        #pragma unroll
        for (int q = 1; q < 8; ++q) mx = fmaxf(mx, v[q]);
        #pragma unroll
        for (int off = 32; off > 0; off >>= 1) mx = fmaxf(mx, __shfl_xor(mx, off));
        float e[8];
        float sum = 0.f;
        #pragma unroll
        for (int q = 0; q < 8; ++q) { e[q] = fexp2((v[q] - mx) * LOG2E); sum += e[q]; }
        #pragma unroll
        for (int off = 32; off > 0; off >>= 1) sum += __shfl_xor(sum, off);
        const float inv = frcp(sum);
        float4 p0 = {e[0]*inv, e[1]*inv, e[2]*inv, e[3]*inv};
        float4 p1 = {e[4]*inv, e[5]*inv, e[6]*inv, e[7]*inv};
        *(float4*)&P[xx][lane*8]   = p0;
        *(float4*)&P[xx][lane*8+4] = p1;
        float* Sg = Sout + ((size_t)b*TX + x0 + xx) * TM + lane*8;
        *(float4*)Sg     = p0;
        *(float4*)(Sg+4) = p1;
    }
    __syncthreads();

    // PV single-pass: wave w owns m in [w*64, w*64+64); all 4 rows per load.
    // memory read exactly once per block; P read as float4 per row per 4-m chunk.
    {
        const int m0 = wave * 64;
        const float* memp = memory + ((size_t)b * TM + m0) * D_MODEL + lane * 4;
        float4 o0 = {0,0,0,0}, o1 = {0,0,0,0}, o2 = {0,0,0,0}, o3 = {0,0,0,0};
        for (int c = 0; c < 16; ++c) {
            float4 p0 = *(const float4*)&P[0][m0 + c*4];
            float4 p1 = *(const float4*)&P[1][m0 + c*4];
            float4 p2 = *(const float4*)&P[2][m0 + c*4];
            float4 p3 = *(const float4*)&P[3][m0 + c*4];
            #pragma unroll
            for (int j = 0; j < 4; ++j) {
                float4 mv = *(const float4*)(memp + (size_t)(c*4 + j) * D_MODEL);
                const float q0 = (j==0)?p0.x:(j==1)?p0.y:(j==2)?p0.z:p0.w;
                const float q1 = (j==0)?p1.x:(j==1)?p1.y:(j==2)?p1.z:p1.w;
                const float q2 = (j==0)?p2.x:(j==1)?p2.y:(j==2)?p2.z:p2.w;
                const float q3 = (j==0)?p3.x:(j==1)?p3.y:(j==2)?p3.z:p3.w;
                o0.x = fmaf(q0, mv.x, o0.x); o0.y = fmaf(q0, mv.y, o0.y);
                o0.z = fmaf(q0, mv.z, o0.z); o0.w = fmaf(q0, mv.w, o0.w);
                o1.x = fmaf(q1, mv.x, o1.x); o1.y = fmaf(q1, mv.y, o1.y);
                o1.z = fmaf(q1, mv.z, o1.z); o1.w = fmaf(q1, mv.w, o1.w);
                o2.x = fmaf(q2, mv.x, o2.x); o2.y = fmaf(q2, mv.y, o2.y);
                o2.z = fmaf(q2, mv.z, o2.z); o2.w = fmaf(q2, mv.w, o2.w);
                o3.x = fmaf(q3, mv.x, o3.x); o3.y = fmaf(q3, mv.y, o3.y);
                o3.z = fmaf(q3, mv.z, o3.z); o3.w = fmaf(q3, mv.w, o3.w);
            }
        }
        *(float4*)&opart[wave][0][lane*4] = o0;
        *(float4*)&opart[wave][1][lane*4] = o1;
        *(float4*)&opart[wave][2][lane*4] = o2;
        *(float4*)&opart[wave][3][lane*4] = o3;
    }
    __syncthreads();

    // combine 8 wave-partials: 1024 outputs, 2 per thread
    {
        #pragma unroll
        for (int k = 0; k < 2; ++k) {
            const int idx = t + k * 512;
            const int row = idx >> 8, d0 = idx & 255;
            float s = 0.f;
            #pragma unroll
            for (int w = 0; w < 8; ++w) s += opart[w][row][d0];
            out[((size_t)b*TX + x0 + row) * D_MODEL + d0] = s;
        }
    }
}

extern "C" void kernel_launch(void* const* d_in, const int* in_sizes, int n_in,
                              void* d_out, int out_size, void* d_ws, size_t ws_size,
                              hipStream_t stream) {
    const float* x    = (const float*)d_in[0];
    const float* mem  = (const float*)d_in[1];
    const int*   mask = (const int*)d_in[2];
    const float* w1   = (const float*)d_in[3];
    const float* b1   = (const float*)d_in[4];
    const float* w2   = (const float*)d_in[5];
    const float* wst  = (const float*)d_in[6];

    float* out  = (float*)d_out;                  // [4*512*256]
    float* Sout = out + 4 * 512 * 256;            // [4*512*512]
    float* E1   = (float*)d_ws;                   // 524288 floats (2 MB), [2048][256]
    float* E2p  = E1 + 4 * 512 * 256;             // 524288 floats (2 MB), packed

    dim3 gg(32, 4, 2);
    gemm_exp2<<<gg, 256, 0, stream>>>(x, mem, w1, b1, w2, E1, E2p);
    fused_tanh_attn<<<512, 512, 0, stream>>>(E1, E2p, mem, mask, wst, out, Sout);
}